// Round 1
// 211.871 us; speedup vs baseline: 1.0818x; 1.0818x over previous
//
#include <hip/hip_runtime.h>
#include <stdint.h>

// RelationalMSG decomposed:
//   msg  = relu(x_s@W1a + x_d@W1b + b1)   ->  Ys = x@W1a, Yd = x@W1b + b1  (dense GEMM, fused x->bf16)
//   agg  = segment_sum(msg, dst)          ->  counting-sort edges by dst, then CSR
//                                             per-node gather+relu+sum (NO atomics)
//   out  = x + relu([x;agg]@W2 + b2)      ->  dense GEMM
// N=50000 (16 | N), E=600000, D=128.
// This revision: 8 dispatches (was 12); packed epilogue stores via column-permuted
// B-fragments; 8-deep MLP in the CSR aggregation; shfl-based scan.

typedef __attribute__((ext_vector_type(8))) short short8;   // 8 bf16 (MFMA A/B frag)
typedef __attribute__((ext_vector_type(4))) float floatx4;  // MFMA C/D frag

#define D 128

static __device__ __forceinline__ unsigned short f2bf(float f) {
    union { float f; unsigned int u; } v; v.f = f;
    unsigned int r = (v.u + 0x7fffu + ((v.u >> 16) & 1u)) >> 16; // RNE
    return (unsigned short)r;
}
static __device__ __forceinline__ float bflo(unsigned int u) {
    union { unsigned int u; float f; } v; v.u = u << 16; return v.f;
}
static __device__ __forceinline__ float bfhi(unsigned int u) {
    union { unsigned int u; float f; } v; v.u = u & 0xffff0000u; return v.f;
}

// B-fragment layouts (column-PERMUTED so each lane's frags hold ADJACENT output cols):
// w1f (gemm1, K=128, 256 out cols): frag[(kk*16+ct)*64+lane][j] =
//      B1[kk*32+(lane>>4)*8+j][ (ct>>2)*64 + 4*(lane&15) + (ct&3) ]
//   B1[k][c] = c<128 ? W1[k][c] : W1[128+k][c-128]   (W1 is [256][128])
// w2f (gemm2, K=256, 128 out cols): frag[(kk*8+ct)*64+lane][j] =
//      W2[kk*32+(lane>>4)*8+j][ (ct>>1)*32 + 2*(lane&15) + (ct&1) ]
// Also zeroes cursor[] (replaces the hipMemsetAsync dispatch).
__global__ void k_convert_w(const float* __restrict__ W1, const float* __restrict__ W2,
                            unsigned short* __restrict__ w1f, unsigned short* __restrict__ w2f,
                            int* __restrict__ cursor, int N) {
    int gid = blockIdx.x * blockDim.x + threadIdx.x; // 65536 threads
    if (gid < N) cursor[gid] = 0;
    if (gid < 32768) {
        int tid = gid;
        int j = tid & 7, lane = (tid >> 3) & 63, ct = (tid >> 9) & 15, kk = tid >> 13;
        int k = kk * 32 + (lane >> 4) * 8 + j;
        int c = ((ct >> 2) << 6) + ((lane & 15) << 2) + (ct & 3);
        float v = (c < 128) ? W1[k * 128 + c] : W1[(128 + k) * 128 + (c - 128)];
        w1f[tid] = f2bf(v);
    } else {
        int tid = gid - 32768;
        int j = tid & 7, lane = (tid >> 3) & 63, ct = (tid >> 9) & 7, kk = tid >> 12;
        int k = kk * 32 + (lane >> 4) * 8 + j;
        int c = ((ct >> 1) << 5) + ((lane & 15) << 1) + (ct & 1);
        w2f[tid] = f2bf(W2[k * 128 + c]);
    }
}

// Y = x @ [W1a | W1b] (+b1 on the Yd half). M=N, K=128, Nout=256.
// Reads fp32 x directly (convert pass fused); wave 0 writes the bf16 xb side-product.
// Block = 4 waves; wave w owns out-cols [w*64, w*64+64). Barrier-free.
// Frag j of wave w holds actual col w*64 + 4*(lane&15) + j  ->  8B ushort4 stores.
__global__ __launch_bounds__(256) void k_gemm1(
    const float* __restrict__ x,
    const unsigned short* __restrict__ w1f,
    const float* __restrict__ b1,
    unsigned short* __restrict__ xb,
    unsigned short* __restrict__ Ys,
    unsigned short* __restrict__ Yd,
    int N, int nTiles)
{
    const int tid = threadIdx.x, w = tid >> 6, lane = tid & 63;
    const int quad = lane >> 4, col = lane & 15;

    short8 wf[4][4];
#pragma unroll
    for (int kk = 0; kk < 4; kk++)
#pragma unroll
        for (int j = 0; j < 4; j++)
            wf[kk][j] = ((const short8*)w1f)[(kk * 16 + w * 4 + j) * 64 + lane];
    float4 bias = make_float4(0.f, 0.f, 0.f, 0.f);
    if (w >= 2) bias = *(const float4*)(b1 + (w - 2) * 64 + col * 4);
    unsigned short* Yhalf = (w < 2) ? Ys : Yd;
    const int cb = (w & 1) * 64;

    for (int t = blockIdx.x; t < nTiles; t += gridDim.x) {
        const int n0 = t * 16;
        const int nr = n0 + col;                 // N % 16 == 0: never out of range
        const float* xrow = x + (long)nr * D;
        floatx4 acc[4];
#pragma unroll
        for (int j = 0; j < 4; j++)
#pragma unroll
            for (int q = 0; q < 4; q++) acc[j][q] = 0.f;
#pragma unroll
        for (int kk = 0; kk < 4; kk++) {
            float4 f0 = *(const float4*)(xrow + kk * 32 + quad * 8);
            float4 f1 = *(const float4*)(xrow + kk * 32 + quad * 8 + 4);
            union { short8 s; unsigned int u[4]; } au;
            asm("v_cvt_pk_bf16_f32 %0, %1, %2" : "=v"(au.u[0]) : "v"(f0.x), "v"(f0.y));
            asm("v_cvt_pk_bf16_f32 %0, %1, %2" : "=v"(au.u[1]) : "v"(f0.z), "v"(f0.w));
            asm("v_cvt_pk_bf16_f32 %0, %1, %2" : "=v"(au.u[2]) : "v"(f1.x), "v"(f1.y));
            asm("v_cvt_pk_bf16_f32 %0, %1, %2" : "=v"(au.u[3]) : "v"(f1.z), "v"(f1.w));
            if (w == 0)
                *(short8*)(xb + (long)nr * D + kk * 32 + quad * 8) = au.s;
#pragma unroll
            for (int j = 0; j < 4; j++)
                acc[j] = __builtin_amdgcn_mfma_f32_16x16x32_bf16(au.s, wf[kk][j], acc[j], 0, 0, 0);
        }
#pragma unroll
        for (int r = 0; r < 4; r++) {
            int n = n0 + quad * 4 + r;
            ushort4 o;
            o.x = f2bf(acc[0][r] + bias.x);
            o.y = f2bf(acc[1][r] + bias.y);
            o.z = f2bf(acc[2][r] + bias.z);
            o.w = f2bf(acc[3][r] + bias.w);
            *(ushort4*)(Yhalf + (long)n * D + cb + col * 4) = o;
        }
    }
}

// ---- counting sort of edges by dst ----
__global__ void k_hist(const int* __restrict__ dst, int* __restrict__ cnt, int E) {
    int i = blockIdx.x * blockDim.x + threadIdx.x;
    if (i < E) atomicAdd(&cnt[dst[i]], 1);
}

// shfl-based block scan (1024 threads = 16 waves, 2 barriers instead of 20).
__global__ void k_scanA(const int* __restrict__ cnt, int* __restrict__ rowptr,
                        int* __restrict__ bsum, int N) {
    __shared__ int ws[16];
    int tid = threadIdx.x, i = blockIdx.x * 1024 + tid;
    int lane = tid & 63, wv = tid >> 6;
    int c = (i < N) ? cnt[i] : 0;
    int incl = c;
#pragma unroll
    for (int off = 1; off < 64; off <<= 1) {
        int t = __shfl_up(incl, off, 64);
        if (lane >= off) incl += t;
    }
    if (lane == 63) ws[wv] = incl;
    __syncthreads();
    if (wv == 0) {
        int v = (lane < 16) ? ws[lane] : 0;
        int s = v;
#pragma unroll
        for (int off = 1; off < 16; off <<= 1) {
            int t = __shfl_up(s, off, 64);
            if (lane >= off) s += t;
        }
        if (lane < 16) ws[lane] = s - v;   // exclusive wave offsets
    }
    __syncthreads();
    if (i < N) rowptr[i] = incl - c + ws[wv];        // exclusive within block
    if (tid == 1023) bsum[blockIdx.x] = ws[15] + incl; // block total
}

// Adds the cross-block offset (scanB fused: per-block 64-lane reduce over <=64 bsums).
__global__ void k_scanC(int* __restrict__ rowptr, int* __restrict__ cursor,
                        const int* __restrict__ bsum, int N, int E, int nb) {
    __shared__ int off_s;
    int tid = threadIdx.x;
    int chunk = blockIdx.x >> 2;  // 256-thread block -> one 1024-node chunk id (uniform)
    if (tid < 64) {
        int v = (tid < chunk && tid < nb) ? bsum[tid] : 0;
#pragma unroll
        for (int off = 32; off; off >>= 1) v += __shfl_down(v, off, 64);
        if (tid == 0) off_s = v;
    }
    __syncthreads();
    int i = blockIdx.x * 256 + tid;
    if (i < N) {
        int r = rowptr[i] + off_s;
        rowptr[i] = r;
        cursor[i] = r;
    }
    if (i == 0) rowptr[N] = E;
}

__global__ void k_scatter(const int* __restrict__ src, const int* __restrict__ dst,
                          int* __restrict__ cursor, int* __restrict__ ssrc, int E) {
    int i = blockIdx.x * blockDim.x + threadIdx.x;
    if (i < E) {
        int p = atomicAdd(&cursor[dst[i]], 1);
        ssrc[p] = src[i];
    }
}

// CSR aggregation: one wave per dst node. agg[n] = sum_e relu(Ys[src_e] + Yd[n]).
// Lane handles 2 of 128 cols (bf16x2). 8-deep MLP: preload 8 indices, issue 8
// independent 256B row reads per round. No atomics.
__global__ __launch_bounds__(256) void k_agg(
    const unsigned short* __restrict__ Ys,
    const unsigned short* __restrict__ Yd,
    const int* __restrict__ rowptr,
    const int* __restrict__ ssrc,
    unsigned short* __restrict__ aggb, int N)
{
    int wv = blockIdx.x * 4 + (threadIdx.x >> 6);
    if (wv >= N) return;
    int lane = threadIdx.x & 63;
    int rp0 = rowptr[wv], rp1 = rowptr[wv + 1];
    unsigned int ydu = *(const unsigned int*)(Yd + (long)wv * D + lane * 2);
    float yd0 = bflo(ydu), yd1 = bfhi(ydu);
    float a0 = 0.f, a1 = 0.f;
    const unsigned short* ysl = Ys + lane * 2;
    int e = rp0;
    for (; e + 8 <= rp1; e += 8) {
        int s[8]; unsigned int u[8];
#pragma unroll
        for (int q = 0; q < 8; q++) s[q] = ssrc[e + q];
#pragma unroll
        for (int q = 0; q < 8; q++) u[q] = *(const unsigned int*)(ysl + (long)s[q] * D);
#pragma unroll
        for (int q = 0; q < 8; q++) {
            a0 += fmaxf(bflo(u[q]) + yd0, 0.f);
            a1 += fmaxf(bfhi(u[q]) + yd1, 0.f);
        }
    }
    for (; e + 4 <= rp1; e += 4) {
        int s[4]; unsigned int u[4];
#pragma unroll
        for (int q = 0; q < 4; q++) s[q] = ssrc[e + q];
#pragma unroll
        for (int q = 0; q < 4; q++) u[q] = *(const unsigned int*)(ysl + (long)s[q] * D);
#pragma unroll
        for (int q = 0; q < 4; q++) {
            a0 += fmaxf(bflo(u[q]) + yd0, 0.f);
            a1 += fmaxf(bfhi(u[q]) + yd1, 0.f);
        }
    }
    for (; e < rp1; e++) {
        unsigned int u0 = *(const unsigned int*)(ysl + (long)ssrc[e] * D);
        a0 += fmaxf(bflo(u0) + yd0, 0.f);
        a1 += fmaxf(bfhi(u0) + yd1, 0.f);
    }
    unsigned int o = (unsigned int)f2bf(a0) | ((unsigned int)f2bf(a1) << 16);
    *(unsigned int*)(aggb + (long)wv * D + lane * 2) = o;
}

// out = x + relu([xb ; aggb] @ W2 + b2). M=N, K=256, Nout=128.
// Block = 4 waves; wave w owns out-cols [w*32, w*32+32). Barrier-free.
// Frag c of wave w holds actual col w*32 + 2*(lane&15) + c  ->  8B float2 stores.
__global__ __launch_bounds__(256) void k_gemm2(
    const unsigned short* __restrict__ xb,
    const unsigned short* __restrict__ aggb,
    const unsigned short* __restrict__ w2f,
    const float* __restrict__ b2,
    const float* __restrict__ x,
    float* __restrict__ out,
    int N, int nTiles)
{
    const int tid = threadIdx.x, w = tid >> 6, lane = tid & 63;
    const int quad = lane >> 4, col = lane & 15;

    short8 wf[8][2];
#pragma unroll
    for (int kk = 0; kk < 8; kk++)
#pragma unroll
        for (int c = 0; c < 2; c++)
            wf[kk][c] = ((const short8*)w2f)[(kk * 8 + w * 2 + c) * 64 + lane];
    float2 bias = *(const float2*)(b2 + w * 32 + col * 2);

    for (int t = blockIdx.x; t < nTiles; t += gridDim.x) {
        const int n0 = t * 16;
        const int nr = n0 + col;                 // N % 16 == 0
        floatx4 acc[2];
#pragma unroll
        for (int c = 0; c < 2; c++)
#pragma unroll
            for (int q = 0; q < 4; q++) acc[c][q] = 0.f;
#pragma unroll
        for (int kk = 0; kk < 8; kk++) {
            const unsigned short* base = (kk < 4) ? xb : aggb;
            short8 a = *(const short8*)(base + (long)nr * D + (kk & 3) * 32 + quad * 8);
            acc[0] = __builtin_amdgcn_mfma_f32_16x16x32_bf16(a, wf[kk][0], acc[0], 0, 0, 0);
            acc[1] = __builtin_amdgcn_mfma_f32_16x16x32_bf16(a, wf[kk][1], acc[1], 0, 0, 0);
        }
#pragma unroll
        for (int r = 0; r < 4; r++) {
            int n = n0 + quad * 4 + r;
            long off = (long)n * D + w * 32 + col * 2;
            float2 xr = *(const float2*)(x + off);
            float v0 = fmaxf(acc[0][r] + bias.x, 0.f);
            float v1 = fmaxf(acc[1][r] + bias.y, 0.f);
            *(float2*)(out + off) = make_float2(xr.x + v0, xr.y + v1);
        }
    }
}

extern "C" void kernel_launch(void* const* d_in, const int* in_sizes, int n_in,
                              void* d_out, int out_size, void* d_ws, size_t ws_size,
                              hipStream_t stream)
{
    const float* x   = (const float*)d_in[0];
    const int* esrc  = (const int*)d_in[1];
    const int* edst  = (const int*)d_in[2];
    const float* W1  = (const float*)d_in[3];
    const float* b1  = (const float*)d_in[4];
    const float* W2  = (const float*)d_in[5];
    const float* b2  = (const float*)d_in[6];
    float* out = (float*)d_out;

    const int ND = in_sizes[0];     // N*D
    const int N  = ND / D;          // 50000
    const int E  = in_sizes[1];     // 600000

    // workspace carve-out (256B-aligned chunks), total ~54 MB
    char* p = (char*)d_ws;
    auto alloc = [&](size_t bytes) { char* r = p; p += (bytes + 255) & ~(size_t)255; return r; };
    unsigned short* Ys   = (unsigned short*)alloc((size_t)ND * 2);
    unsigned short* Yd   = (unsigned short*)alloc((size_t)ND * 2);
    unsigned short* xb   = (unsigned short*)alloc((size_t)ND * 2);
    unsigned short* aggb = (unsigned short*)alloc((size_t)ND * 2);
    unsigned short* w1f  = (unsigned short*)alloc(32768 * 2);
    unsigned short* w2f  = (unsigned short*)alloc(32768 * 2);
    int* rowptr = (int*)alloc((size_t)(N + 1) * 4);
    int* cursor = (int*)alloc((size_t)N * 4);
    int* bsum   = (int*)alloc(64 * 4);
    int* ssrc   = (int*)alloc((size_t)E * 4);

    const int nTiles = N / 16;          // 3125 (N % 16 == 0)
    const int nb = (N + 1023) / 1024;   // 49 (<=64)

    k_convert_w<<<256, 256, 0, stream>>>(W1, W2, w1f, w2f, cursor, N);
    k_gemm1<<<1024, 256, 0, stream>>>(x, w1f, b1, xb, Ys, Yd, N, nTiles);
    k_hist<<<(E + 255) / 256, 256, 0, stream>>>(edst, cursor, E);
    k_scanA<<<nb, 1024, 0, stream>>>(cursor, rowptr, bsum, N);
    k_scanC<<<(N + 255) / 256, 256, 0, stream>>>(rowptr, cursor, bsum, N, E, nb);
    k_scatter<<<(E + 255) / 256, 256, 0, stream>>>(esrc, edst, cursor, ssrc, E);
    k_agg<<<(N + 3) / 4, 256, 0, stream>>>(Ys, Yd, rowptr, ssrc, aggb, N);
    k_gemm2<<<1024, 256, 0, stream>>>(xb, aggb, w2f, b2, x, out, N, nTiles);
}